// Round 5
// baseline (160.649 us; speedup 1.0000x reference)
//
#include <hip/hip_runtime.h>
#include <hip/hip_cooperative_groups.h>

namespace cg = cooperative_groups;

#define NR 24
#define NBATCH 2
#define NFEAT 2
#define NX 256
#define NY 256
#define NZ 16
#define SLOTS 27          // bins -1..25 unwrapped (no mod-24 in hot loop)
#define ROWS_PER_BLK 2
#define NBLK_PER_BF 256   // 128 row-pairs x 2 col-halves
#define NPART (NR * NZ)   // 384 outputs per bf
#define NOUT (NBATCH * NFEAT * NPART)
#define NBLOCKS (NBATCH * NFEAT * NBLK_PER_BF)   // 1024 = 4/CU, co-resident

// Fused single-launch kernel (round 5).
// Budget model from rounds 0-4: fill 42.7 (harness, fixed) + ~8 us PER LAUNCH
// overhead + partial ~13 + reduce ~3. Fusing the two stages via cooperative
// grid sync removes one launch (~8 us).
//
// Phase 1 (identical numerics to round 4): per (bf,row-pair,col-half) block,
// circular 3-tap binning in "bin units" (theta*12/pi), LDS transposed
// red[slot][tid] -> bank = tid%32, conflict-free regardless of data-dependent
// slot. 1024 blocks x 27.6 KiB = 4 blocks/CU resident (<=5 by LDS).
// Phase 2: blocks 0..383, one wave per output, float4 x 64 lanes = 256
// partials, shuffle reduce, sqrt.
__global__ __launch_bounds__(256) void grx_fused(
    const float* __restrict__ x,
    const float* __restrict__ com_real,
    const float* __restrict__ com_imag,
    float* __restrict__ ws,
    float* __restrict__ out)
{
    __shared__ float red[SLOTS][256];   // 27.6 KiB

    const int tid  = threadIdx.x;
    const int z    = tid & 15;
    const int c0   = tid >> 4;
    const int half = blockIdx.x & 1;
    const int rp   = (blockIdx.x >> 1) & 127;
    const int bf   = blockIdx.x >> 8;          // 0..3

    // cooperative vectorized zero: 1728 float4, 7 b128 stores/thread
    float4* r4 = (float4*)&red[0][0];
    #pragma unroll
    for (int i = 0; i < 7; ++i) {
        const int idx = tid + i * 256;
        if (idx < (SLOTS * 256 / 4)) r4[idx] = make_float4(0.f, 0.f, 0.f, 0.f);
    }
    __syncthreads();

    const float comr = com_real[bf * NZ + z];
    const float comi = com_imag[bf * NZ + z];

    // atan poly coefficients pre-scaled by 12/pi (result directly in bin units)
    const float A4 = 0.0795845f;
    const float A3 = -0.3251843f;
    const float A2 = 0.6880875f;
    const float A1 = -1.2616510f;
    const float A0 = 3.8192070f;
    const float C_E = -3.4269908169872414f;    // -50*(pi/12)^2

    const int col0 = c0 + (half << 7);
    float* mycol = &red[0][tid];               // column owned by this thread

    #pragma unroll
    for (int rr_ = 0; rr_ < ROWS_PER_BLK; ++rr_) {
        const int row   = rp * ROWS_PER_BLK + rr_;
        const float dyv = (float)row - comi;
        const float ady = fabsf(dyv);
        const float* xq = x + ((size_t)(bf * NX + row)) * (NY * NZ) + (col0 * NZ + z);
        float dxv = (float)col0 - comr;          // col start; += 16 per iter

        #pragma unroll
        for (int kk = 0; kk < 8; ++kk) {
            const float xv = xq[kk * 256];       // 64 consecutive floats per wave

            // ---- custom atan2 in bin units (|err| ~1e-5 rad equiv) ----
            const float adx = fabsf(dxv);
            const float mn  = fminf(adx, ady);
            const float mx  = fmaxf(adx, ady);
            const float t   = mn * __builtin_amdgcn_rcpf(fmaxf(mx, 1e-30f));
            const float r2  = t * t;
            float p = fmaf(r2, A4, A3);
            p = fmaf(r2, p, A2);
            p = fmaf(r2, p, A1);
            p = fmaf(r2, p, A0);
            float psi = t * p;                   // [0, 6]
            if (ady > adx)  psi = 6.0f - psi;
            if (dxv < 0.0f) psi = 12.0f - psi;
            psi = copysignf(psi, dyv);           // (-12, 12]
            dxv += 16.0f;

            // ---- 3-neighbor circular binning, unwrapped slots ----
            const float nf  = rintf(psi);
            const float f   = psi - nf;          // [-0.5, 0.5]
            const int base  = (int)nf + 12;      // [0, 24] -> slots base..base+2

            const float fm = f + 1.0f;
            const float fp = f - 1.0f;
            const float wm = __expf(C_E * fm * fm) * xv;  // -> slot base
            const float w0 = __expf(C_E * f  * f ) * xv;  // -> slot base+1
            const float wp = __expf(C_E * fp * fp) * xv;  // -> slot base+2

            // conflict-free 3-tap RMW down one bank column
            float* pb = mycol + (base << 8);     // &red[base][tid]
            float a0 = pb[0];
            float a1 = pb[256];
            float a2 = pb[512];
            a0 += wm; a1 += w0; a2 += wp;
            pb[0]   = a0;
            pb[256] = a1;
            pb[512] = a2;
        }
    }

    __syncthreads();

    // Phase-1 tail: reduce 16 col-phases per (r,z); fold wrap slots; store partials.
    const int l = blockIdx.x & (NBLK_PER_BF - 1);
    for (int o = tid; o < NPART; o += 256) {
        const int r  = o >> 4;
        const int zz = o & 15;
        float s = 0.0f;
        #pragma unroll
        for (int c = 0; c < 16; ++c) {
            float v = red[r + 1][c * 16 + zz];   // slot r+1 holds bin r
            if (r == 0)  v += red[25][c * 16 + zz];  // bin 24 == 0
            if (r == 1)  v += red[26][c * 16 + zz];  // bin 25 == 1
            if (r == 23) v += red[0][c * 16 + zz];   // bin -1 == 23
            s += v;
        }
        ws[((size_t)(bf * NPART + o) * NBLK_PER_BF) + l] = s;
    }

    // ---- grid-wide sync, then phase 2 on blocks 0..383 ----
    cg::this_grid().sync();

    if (blockIdx.x < NOUT / 4) {
        const int o    = blockIdx.x * 4 + (tid >> 6);   // one output per wave
        const int lane = tid & 63;
        const float4 v = ((const float4*)(ws + (size_t)o * NBLK_PER_BF))[lane];
        float s = v.x + v.y + v.z + v.w;
        #pragma unroll
        for (int off = 32; off; off >>= 1) s += __shfl_down(s, off, 64);
        if (lane == 0) {
            // 2 * 1/(sigma*sqrt(2*pi))
            out[o] = sqrtf(7.9788456080286535f * s);
        }
    }
}

extern "C" void kernel_launch(void* const* d_in, const int* in_sizes, int n_in,
                              void* d_out, int out_size, void* d_ws, size_t ws_size,
                              hipStream_t stream)
{
    const float* x  = (const float*)d_in[0];
    const float* cr = (const float*)d_in[1];
    const float* ci = (const float*)d_in[2];
    float* out = (float*)d_out;
    float* ws  = (float*)d_ws;

    void* args[] = {(void*)&x, (void*)&cr, (void*)&ci, (void*)&ws, (void*)&out};
    hipLaunchCooperativeKernel((const void*)grx_fused,
                               dim3(NBLOCKS), dim3(256), args, 0, stream);
}

// Round 6
// 76.073 us; speedup vs baseline: 2.1118x; 2.1118x over previous
//
#include <hip/hip_runtime.h>

#define NR 24
#define NBATCH 2
#define NFEAT 2
#define NX 256
#define NY 256
#define NZ 16
#define SLOTS 27          // bins -1..25 unwrapped (no mod-24 in hot loop)
#define NBLK_PER_BF 512   // 256 rows x 2 col-halves (1 row per block)
#define NPART (NR * NZ)   // 384 outputs per bf
#define NOUT (NBATCH * NFEAT * NPART)

// Stage 1: per (bf, row, col-half) block. Thread = (col-phase c0, z).
// Circular binning: each pixel hits only 3 of 24 radii (sigma=0.1 << spacing 0.262).
// Works in "bin units" (theta * 12/pi). LDS transposed red[slot][tid]:
// bank = tid%32, conflict-free (2-way l/l+32 aliasing is free, m136) regardless
// of the data-dependent slot.
//
// Round-5 lessons: grid.sync() costs ~70 us on MI355X (NEVER worth one launch);
// VALUBusy inside phase1 is ~36% -> latency-bound. So: back to 2 launches, and
// raise occupancy 16 -> 20 waves/CU by going to 1 row/block (2048 blocks; LDS
// 27.6 KiB caps residency at 5 blocks/CU, grid no longer the cap at 4).
__global__ __launch_bounds__(256) void grx_partial(
    const float* __restrict__ x,
    const float* __restrict__ com_real,
    const float* __restrict__ com_imag,
    float* __restrict__ ws)
{
    __shared__ float red[SLOTS][256];   // 27.6 KiB -> 5 blocks/CU resident

    const int tid  = threadIdx.x;
    const int z    = tid & 15;
    const int c0   = tid >> 4;
    const int half = blockIdx.x & 1;
    const int row  = (blockIdx.x >> 1) & (NX - 1);
    const int bf   = blockIdx.x >> 9;          // 0..3

    // cooperative vectorized zero: 1728 float4, 7 b128 stores/thread
    float4* r4 = (float4*)&red[0][0];
    #pragma unroll
    for (int i = 0; i < 7; ++i) {
        const int idx = tid + i * 256;
        if (idx < (SLOTS * 256 / 4)) r4[idx] = make_float4(0.f, 0.f, 0.f, 0.f);
    }
    __syncthreads();

    const float comr = com_real[bf * NZ + z];
    const float comi = com_imag[bf * NZ + z];

    // atan poly coefficients pre-scaled by 12/pi (result directly in bin units)
    const float A4 = 0.0795845f;
    const float A3 = -0.3251843f;
    const float A2 = 0.6880875f;
    const float A1 = -1.2616510f;
    const float A0 = 3.8192070f;
    const float C_E = -3.4269908169872414f;    // -50*(pi/12)^2

    const int col0 = c0 + (half << 7);
    float* mycol = &red[0][tid];               // column owned by this thread

    const float dyv = (float)row - comi;
    const float ady = fabsf(dyv);
    const float* xq = x + ((size_t)(bf * NX + row)) * (NY * NZ) + (col0 * NZ + z);
    float dxv = (float)col0 - comr;            // col start; += 16 per iter

    #pragma unroll
    for (int kk = 0; kk < 8; ++kk) {
        const float xv = xq[kk * 256];         // 64 consecutive floats per wave

        // ---- custom atan2 in bin units (|err| ~1e-5 rad equiv) ----
        const float adx = fabsf(dxv);
        const float mn  = fminf(adx, ady);
        const float mx  = fmaxf(adx, ady);
        const float t   = mn * __builtin_amdgcn_rcpf(fmaxf(mx, 1e-30f));
        const float r2  = t * t;
        float p = fmaf(r2, A4, A3);
        p = fmaf(r2, p, A2);
        p = fmaf(r2, p, A1);
        p = fmaf(r2, p, A0);
        float psi = t * p;                     // [0, 6]
        if (ady > adx)  psi = 6.0f - psi;
        if (dxv < 0.0f) psi = 12.0f - psi;
        psi = copysignf(psi, dyv);             // (-12, 12]
        dxv += 16.0f;

        // ---- 3-neighbor circular binning, unwrapped slots ----
        const float nf  = rintf(psi);
        const float f   = psi - nf;            // [-0.5, 0.5]
        const int base  = (int)nf + 12;        // [0, 24] -> slots base..base+2

        const float fm = f + 1.0f;
        const float fp = f - 1.0f;
        const float wm = __expf(C_E * fm * fm) * xv;  // -> slot base
        const float w0 = __expf(C_E * f  * f ) * xv;  // -> slot base+1
        const float wp = __expf(C_E * fp * fp) * xv;  // -> slot base+2

        // conflict-free 3-tap RMW down one bank column
        float* pb = mycol + (base << 8);       // &red[base][tid]
        float a0 = pb[0];
        float a1 = pb[256];
        float a2 = pb[512];
        a0 += wm; a1 += w0; a2 += wp;
        pb[0]   = a0;
        pb[256] = a1;
        pb[512] = a2;
    }

    __syncthreads();

    // Reduce over 16 col-phases per (r,z); fold wrap slots; transposed store.
    const int l = blockIdx.x & (NBLK_PER_BF - 1);
    for (int o = tid; o < NPART; o += 256) {
        const int r  = o >> 4;
        const int zz = o & 15;
        float s = 0.0f;
        #pragma unroll
        for (int c = 0; c < 16; ++c) {
            float v = red[r + 1][c * 16 + zz];   // slot r+1 holds bin r
            if (r == 0)  v += red[25][c * 16 + zz];  // bin 24 == 0
            if (r == 1)  v += red[26][c * 16 + zz];  // bin 25 == 1
            if (r == 23) v += red[0][c * 16 + zz];   // bin -1 == 23
            s += v;
        }
        ws[((size_t)(bf * NPART + o) * NBLK_PER_BF) + l] = s;
    }
}

// Stage 2: 384 blocks, one wave per output; 8 contiguous floats (2 x float4)
// per lane covers the 512 partials; shuffle reduce; lane 0 writes sqrt.
__global__ __launch_bounds__(256) void grx_reduce(
    const float* __restrict__ ws, float* __restrict__ out)
{
    const int o    = blockIdx.x * 4 + (threadIdx.x >> 6);  // 0..1535
    const int lane = threadIdx.x & 63;
    const float4* base = (const float4*)(ws + (size_t)o * NBLK_PER_BF);
    const float4 v0 = base[lane];
    const float4 v1 = base[lane + 64];
    float s = (v0.x + v0.y + v0.z + v0.w) + (v1.x + v1.y + v1.z + v1.w);

    #pragma unroll
    for (int off = 32; off; off >>= 1) s += __shfl_down(s, off, 64);

    if (lane == 0) {
        // 2 * 1/(sigma*sqrt(2*pi))
        out[o] = sqrtf(7.9788456080286535f * s);
    }
}

extern "C" void kernel_launch(void* const* d_in, const int* in_sizes, int n_in,
                              void* d_out, int out_size, void* d_ws, size_t ws_size,
                              hipStream_t stream)
{
    const float* x  = (const float*)d_in[0];
    const float* cr = (const float*)d_in[1];
    const float* ci = (const float*)d_in[2];
    float* out = (float*)d_out;
    float* ws  = (float*)d_ws;

    grx_partial<<<dim3(NBATCH * NFEAT * NBLK_PER_BF), dim3(256), 0, stream>>>(x, cr, ci, ws);
    grx_reduce<<<dim3(NOUT / 4), dim3(256), 0, stream>>>(ws, out);
}